// Round 13
// baseline (229.843 us; speedup 1.0000x reference)
//
#include <hip/hip_runtime.h>

// Problem constants: x [B=2, C=512, H=64, W=64], 32 groups, N = H*W = 4096.
#define BB 2
#define CC 512
#define NS 4096
#define NGROUP 32
#define TILE 128
#define RSTRIDE 132   // repack LDS row stride (floats): 128 + 4 pad

typedef __bf16 bf16_8 __attribute__((ext_vector_type(8)));
typedef __bf16 bf16_4 __attribute__((ext_vector_type(4)));
typedef float f32_4 __attribute__((ext_vector_type(4)));

#define SMEM_BYTES 65536   // core-A kernels: 2 x (16KB A + 16KB B) double-buffer
#define SMEM256 131072     // core F: 2 x (32KB A + 32KB B) double-buffer

__device__ __forceinline__ void gld_lds16(const __bf16* g, __bf16* l) {
  __builtin_amdgcn_global_load_lds(
      (const __attribute__((address_space(1))) unsigned int*)g,
      (__attribute__((address_space(3))) unsigned int*)l, 16, 0, 0);
}

// ---------------- prep: weight cvt (blocks 0-1023) + GN stats partials (1024-1279) ----
// Stats: per-(group, quarter-chunk) PARTIAL sums stored plain (no atomics, no
// zeroing) to st[g*8 + ch*2 + {0,1}]; gn_apply_t sums the 4 partials.
__global__ __launch_bounds__(256) void prep(const float* __restrict__ w0, const float* __restrict__ w1,
                                            const float* __restrict__ w2, const float* __restrict__ w3,
                                            __bf16* __restrict__ o0, __bf16* __restrict__ o1,
                                            __bf16* __restrict__ o2, __bf16* __restrict__ o3,
                                            const float* __restrict__ x,
                                            float* __restrict__ st) {
  const int bid = blockIdx.x;
  if (bid >= 1024) {
    const int idx = bid - 1024;
    const int g = idx >> 2;               // 0..63: b*32+group
    const int ch = idx & 3;               // quarter-chunk of the group
    const float4* p = (const float4*)(x + (size_t)g * 65536 + (size_t)ch * 16384);
    float s = 0.f, q = 0.f;
    for (int i = threadIdx.x; i < 4096; i += 256) {
      float4 v = p[i];
      s += v.x + v.y + v.z + v.w;
      q += v.x * v.x + v.y * v.y + v.z * v.z + v.w * v.w;
    }
#pragma unroll
    for (int off = 32; off > 0; off >>= 1) {
      s += __shfl_down(s, off, 64);
      q += __shfl_down(q, off, 64);
    }
    __shared__ float ls[4], lq[4];
    int wave = threadIdx.x >> 6, lane = threadIdx.x & 63;
    if (lane == 0) { ls[wave] = s; lq[wave] = q; }
    __syncthreads();
    if (threadIdx.x == 0) {
      st[g * 8 + ch * 2 + 0] = ls[0] + ls[1] + ls[2] + ls[3];
      st[g * 8 + ch * 2 + 1] = lq[0] + lq[1] + lq[2] + lq[3];
    }
    return;
  }
  int tsel = bid >> 8;
  int i = (bid & 255) * 256 + threadIdx.x;
  const float* src = tsel == 0 ? w0 : tsel == 1 ? w1 : tsel == 2 ? w2 : w3;
  __bf16* dst = tsel == 0 ? o0 : tsel == 1 ? o1 : tsel == 2 ? o2 : o3;
  float4 v = ((const float4*)src)[i];
  bf16_4 r;
  r[0] = (__bf16)v.x; r[1] = (__bf16)v.y; r[2] = (__bf16)v.z; r[3] = (__bf16)v.w;
  ((bf16_4*)dst)[i] = r;
}

// Normalize + transpose: x[b][c][n] (fp32) -> hnT[b][n][c] (bf16), 32x32 tiles via LDS.
// Finalizes mean/rstd from the 4 per-chunk (S,Q) partials.
__global__ __launch_bounds__(256) void gn_apply_t(const float* __restrict__ x,
                                                  const float* __restrict__ st,
                                                  const float* __restrict__ gamma,
                                                  const float* __restrict__ beta,
                                                  __bf16* __restrict__ hnT) {
  __shared__ float tile[32][33];
  int b = blockIdx.z;
  int c0 = blockIdx.y * 32;
  int n0 = blockIdx.x * 32;
  int tx = threadIdx.x;  // 0..31
  int ty = threadIdx.y;  // 0..7
  const float* xb = x + (size_t)b * CC * NS;
#pragma unroll
  for (int i = 0; i < 4; i++) {
    int c = c0 + ty + i * 8;
    int g8 = (b * NGROUP + (c >> 4)) * 8;
    float S = st[g8 + 0] + st[g8 + 2] + st[g8 + 4] + st[g8 + 6];
    float Q = st[g8 + 1] + st[g8 + 3] + st[g8 + 5] + st[g8 + 7];
    float mean = S * (1.f / 65536.f);
    float var = Q * (1.f / 65536.f) - mean * mean;
    float rstd = rsqrtf(var + 1e-6f);
    float v = xb[(size_t)c * NS + n0 + tx];
    tile[ty + i * 8][tx] = (v - mean) * rstd * gamma[c] + beta[c];
  }
  __syncthreads();
  __bf16* out = hnT + (size_t)b * NS * CC;
#pragma unroll
  for (int i = 0; i < 4; i++) {
    int n = n0 + ty + i * 8;
    out[(size_t)n * CC + c0 + tx] = (__bf16)tile[tx][ty + i * 8];
  }
}

// ======== Core A (double-buffered): 512 threads, 8 waves, 64x32/wave, BK=64 ========
__device__ __forceinline__ void gemm_core8(const __bf16* __restrict__ A, const __bf16* __restrict__ B,
                                           int K, int lda, int ldb,
                                           __bf16* lds, f32_4 (&acc)[4][2]) {
  const int t = threadIdx.x;
  const int lane = t & 63;
  const int wave = t >> 6;
  const int lrow = lane & 15, quad = lane >> 4;
  const int wrow = (wave >> 2) * 64, wcol = (wave & 3) * 32;
  const int co = (quad ^ ((lrow >> 1) & 3)) * 8;   // swizzled read chunk
  const int r0 = t >> 2;                            // 0..127: staged row
  const int kp = ((t & 3) ^ ((t >> 3) & 3)) * 8;   // swizzled staged global chunk
  const __bf16* pA = A + (size_t)r0 * lda + kp;
  const __bf16* pB = B + (size_t)r0 * ldb + kp;
  // prologue: stage k0=0 into buf0
  {
    __bf16* lA = lds;
    __bf16* lB = lds + 8192;
    gld_lds16(pA,      &lA[t * 8]);
    gld_lds16(pA + 32, &lA[4096 + t * 8]);
    gld_lds16(pB,      &lB[t * 8]);
    gld_lds16(pB + 32, &lB[4096 + t * 8]);
  }
  int buf = 0;
  for (int k0 = 0; k0 < K; k0 += 64, buf ^= 1) {
    __syncthreads();   // drains buf's loads (prefetched last iter); protects buf^1 overwrite
    if (k0 + 64 < K) {
      __bf16* lA = lds + (buf ^ 1) * 16384;
      __bf16* lB = lA + 8192;
      gld_lds16(pA + k0 + 64, &lA[t * 8]);
      gld_lds16(pA + k0 + 96, &lA[4096 + t * 8]);
      gld_lds16(pB + k0 + 64, &lB[t * 8]);
      gld_lds16(pB + k0 + 96, &lB[4096 + t * 8]);
    }
    const __bf16* bA = lds + buf * 16384;
    const __bf16* bB = bA + 8192;
#pragma unroll
    for (int ks = 0; ks < 2; ks++) {
      const __bf16* la = bA + ks * 4096;
      const __bf16* lb = bB + ks * 4096;
      bf16_8 af[4], bfr[2];
#pragma unroll
      for (int i = 0; i < 4; i++)
        af[i] = *(const bf16_8*)&la[(wrow + i * 16 + lrow) * 32 + co];
#pragma unroll
      for (int j = 0; j < 2; j++)
        bfr[j] = *(const bf16_8*)&lb[(wcol + j * 16 + lrow) * 32 + co];
#pragma unroll
      for (int i = 0; i < 4; i++)
#pragma unroll
        for (int j = 0; j < 2; j++)
          acc[i][j] = __builtin_amdgcn_mfma_f32_16x16x32_bf16(af[i], bfr[j], acc[i][j], 0, 0, 0);
    }
  }
}

// Repack epilogue for core A (512 threads). lsr unions with dead staging LDS.
__device__ __forceinline__ void stage_acc8(float* ls, const f32_4 (&acc)[4][2], int pass) {
  const int t = threadIdx.x;
  const int lane = t & 63, wave = t >> 6;
  const int lrow = lane & 15, quad = lane >> 4;
  const int wrow = (wave >> 2) * 64, wcol = (wave & 3) * 32;
  if ((wrow >> 6) == pass) {
#pragma unroll
    for (int i = 0; i < 4; i++)
#pragma unroll
      for (int r = 0; r < 4; r++)
#pragma unroll
        for (int jj = 0; jj < 2; jj++)
          ls[(i * 16 + quad * 4 + r) * RSTRIDE + wcol + jj * 16 + lrow] = acc[i][jj][r];
  }
}

__device__ __forceinline__ void drain_bf16_8(const float* ls, __bf16* gdst, int ldg) {
  const int t = threadIdx.x;
#pragma unroll
  for (int k2 = 0; k2 < 4; k2++) {
    int idx = k2 * 512 + t;
    int row = idx >> 5, col = (idx & 31) * 4;
    f32_4 v = *(const f32_4*)&ls[row * RSTRIDE + col];
    bf16_4 o;
    o[0] = (__bf16)v[0]; o[1] = (__bf16)v[1]; o[2] = (__bf16)v[2]; o[3] = (__bf16)v[3];
    *(bf16_4*)&gdst[(size_t)row * ldg + col] = o;
  }
}

// ======== Core F: 256x256 tile, 512 threads, BK=64, ONE sync per K-tile ========
// Best-known e_gemm core (equal to all 6 alternatives; simplest). See round-9 notes.
__device__ __forceinline__ void gemm_coreF(const __bf16* __restrict__ A,
                                           const __bf16* __restrict__ B,
                                           int K, int lda, int ldb,
                                           __bf16* lds, f32_4 (&acc)[8][4]) {
  const int t = threadIdx.x;
  const int lane = t & 63;
  const int wave = t >> 6;
  const int lrow = lane & 15, quad = lane >> 4;
  const int wm = wave >> 2, wn = wave & 3;
  const int r0 = t >> 2;                            // 0..127: staged row within half
  const int kp = ((t & 3) ^ ((t >> 3) & 3)) * 8;    // swizzled staged global chunk
  const __bf16* gA0 = A + (size_t)r0 * lda + kp;
  const __bf16* gA1 = A + (size_t)(r0 + 128) * lda + kp;
  const __bf16* gB0 = B + (size_t)r0 * ldb + kp;
  const __bf16* gB1 = B + (size_t)(r0 + 128) * ldb + kp;
  const int co = (quad ^ ((lrow >> 1) & 3)) * 8;    // swizzled read chunk
  const int aoff = (wm * 128 + lrow) * 32 + co;
  const int boff = 16384 + (wn * 64 + lrow) * 32 + co;
  const int KT = K >> 6;

  // prologue: stage K-tile 0 into buf0 (8 gld_lds)
  {
    __bf16* d = lds + t * 8;
    gld_lds16(gA0,      d);            // A ks0 rows 0-127
    gld_lds16(gA1,      d + 4096);     // A ks0 rows 128-255
    gld_lds16(gA0 + 32, d + 8192);     // A ks1 rows 0-127
    gld_lds16(gA1 + 32, d + 12288);    // A ks1 rows 128-255
    gld_lds16(gB0,      d + 16384);    // B ks0 rows 0-127
    gld_lds16(gB1,      d + 20480);    // B ks0 rows 128-255
    gld_lds16(gB0 + 32, d + 24576);    // B ks1 rows 0-127
    gld_lds16(gB1 + 32, d + 28672);    // B ks1 rows 128-255
  }
  int buf = 0;
  for (int kt = 0; kt < KT; ++kt, buf ^= 1) {
    __syncthreads();   // drains prev stage (landed during prev tile); WAR-safe
    if (kt + 1 < KT) {
      __bf16* d = lds + (buf ^ 1) * 32768 + t * 8;
      const int go = (kt + 1) * 64;
      gld_lds16(gA0 + go,      d);
      gld_lds16(gA1 + go,      d + 4096);
      gld_lds16(gA0 + go + 32, d + 8192);
      gld_lds16(gA1 + go + 32, d + 12288);
      gld_lds16(gB0 + go,      d + 16384);
      gld_lds16(gB1 + go,      d + 20480);
      gld_lds16(gB0 + go + 32, d + 24576);
      gld_lds16(gB1 + go + 32, d + 28672);
    }
    const __bf16* bb = lds + buf * 32768;
#pragma unroll
    for (int ks = 0; ks < 2; ks++) {
      bf16_8 af[8], bv[4];
#pragma unroll
      for (int f = 0; f < 8; f++)
        af[f] = *(const bf16_8*)&bb[aoff + f * 512 + ks * 8192];
#pragma unroll
      for (int j = 0; j < 4; j++)
        bv[j] = *(const bf16_8*)&bb[boff + j * 512 + ks * 8192];
#pragma unroll
      for (int f = 0; f < 8; f++)
#pragma unroll
        for (int j = 0; j < 4; j++)
          acc[f][j] = __builtin_amdgcn_mfma_f32_16x16x32_bf16(af[f], bv[j], acc[f][j], 0, 0, 0);
    }
  }
}

// ---------------- S-GEMM with fused exp + row-sum (core F, 512 blocks) ---------------
__global__ __launch_bounds__(512, 2) void e_gemm256(const __bf16* __restrict__ qT,
                                                    const __bf16* __restrict__ kT,
                                                    __bf16* __restrict__ E,
                                                    float* __restrict__ l,
                                                    float scale) {
  extern __shared__ __bf16 ldsdyn[];
  const int bid = blockIdx.x;
  const int lin = (bid & 7) * 64 + (bid >> 3);   // XCD-chunked (512 % 8 == 0)
  const int b = lin >> 8;
  const int rm = lin & 255;
  // 8x4 tile rectangles so the 32 concurrent blocks of an XCD share panels.
  const int R = rm >> 5, s = rm & 31;
  const int mt = (R >> 2) * 8 + (s >> 2);
  const int nt = (R & 3) * 4 + (s & 3);
  const int m0 = mt * 256, n0 = nt * 256;
  const long long sBNC = (long long)NS * CC;
  const long long sBNN = (long long)NS * NS;
  const __bf16* Ap = qT + (size_t)b * sBNC + (size_t)m0 * CC;
  const __bf16* Bp = kT + (size_t)b * sBNC + (size_t)n0 * CC;

  f32_4 acc[8][4];
#pragma unroll
  for (int i = 0; i < 8; i++)
#pragma unroll
    for (int j = 0; j < 4; j++) acc[i][j] = {0.f, 0.f, 0.f, 0.f};

  gemm_coreF(Ap, Bp, CC, CC, CC, ldsdyn, acc);

  const int t = threadIdx.x;
  const int lane = t & 63, wave = t >> 6;
  const int lrow = lane & 15, quad = lane >> 4;
  const int wm = wave >> 2, wn = wave & 3;
  __bf16* Ep = E + (size_t)b * sBNN;
  float* lp = l + (size_t)b * NS;
#pragma unroll
  for (int i = 0; i < 8; i++) {
#pragma unroll
    for (int r = 0; r < 4; r++) {
      int gm = m0 + wm * 128 + i * 16 + quad * 4 + r;
      float rp = 0.f;
#pragma unroll
      for (int j = 0; j < 4; j++) {
        int gn = n0 + wn * 64 + j * 16 + lrow;
        float ev = __expf(acc[i][j][r] * scale);
        rp += ev;
        Ep[(size_t)gm * NS + gn] = (__bf16)ev;
      }
      rp += __shfl_down(rp, 8, 16);
      rp += __shfl_down(rp, 4, 16);
      rp += __shfl_down(rp, 2, 16);
      rp += __shfl_down(rp, 1, 16);
      if (lrow == 0) atomicAdd(&lp[gm], rp);
    }
  }
}

// ---------------- attn*V FULL-K GEMM with fused softmax division (core A) ----------
// aoT[b][n][c] = (sum_j E[n,j] vv[c,j]) / l[n]  (bf16). 256 blocks = 1 round,
// K = NS = 4096, no split partials, no reduce pass. Full-K fp32 accumulation +
// single bf16 rounding (more accurate than the old 4-partial path).
__global__ __launch_bounds__(512, 4) void ao_full(const __bf16* __restrict__ E,
                                                  const __bf16* __restrict__ vv,
                                                  const float* __restrict__ l,
                                                  __bf16* __restrict__ aoT) {
  __shared__ char smem[SMEM_BYTES];
  __bf16* lds = (__bf16*)smem;
  float* lsr = (float*)smem;
  const int bid = blockIdx.x;
  const int lin = (bid & 7) * 32 + (bid >> 3);   // XCD-chunked (256 % 8 == 0)
  const int b = lin >> 7;
  const int rm = lin & 127;
  const int mt = rm >> 2;                        // 0..31 over NS rows
  const int nt = rm & 3;                         // 0..3 over CC cols
  const int m0 = mt * TILE, n0 = nt * TILE;
  const long long sBNN = (long long)NS * NS;
  const long long sBCN = (long long)CC * NS;
  const long long sBNC = (long long)NS * CC;
  const __bf16* Ap = E + (size_t)b * sBNN + (size_t)m0 * NS;
  const __bf16* Bp = vv + (size_t)b * sBCN + (size_t)n0 * NS;
  const float* lp = l + (size_t)b * NS;
  __bf16* Cp = aoT + (size_t)b * sBNC;

  f32_4 acc[4][2];
#pragma unroll
  for (int i = 0; i < 4; i++)
#pragma unroll
    for (int j = 0; j < 2; j++) acc[i][j] = {0.f, 0.f, 0.f, 0.f};

  gemm_core8(Ap, Bp, NS, NS, NS, lds, acc);

  const int t = threadIdx.x;
#pragma unroll
  for (int p = 0; p < 2; p++) {
    __syncthreads();
    stage_acc8(lsr, acc, p);
    __syncthreads();
#pragma unroll
    for (int k2 = 0; k2 < 4; k2++) {
      int idx = k2 * 512 + t;
      int row = idx >> 5, col = (idx & 31) * 4;
      int gm = m0 + p * 64 + row;
      float inv = 1.f / lp[gm];
      f32_4 v = *(const f32_4*)&lsr[row * RSTRIDE + col];
      bf16_4 o;
      o[0] = (__bf16)(v[0] * inv); o[1] = (__bf16)(v[1] * inv);
      o[2] = (__bf16)(v[2] * inv); o[3] = (__bf16)(v[3] * inv);
      *(bf16_4*)&Cp[(size_t)gm * CC + n0 + col] = o;
    }
  }
}

// ---------------- Fused Q/K/V projections (one dispatch, 768 blocks, core A) ----------
__global__ __launch_bounds__(512, 4) void qkv_gemm(const __bf16* __restrict__ hnT,
                                                   const __bf16* __restrict__ Wq,
                                                   const __bf16* __restrict__ Wk,
                                                   const __bf16* __restrict__ Wv,
                                                   const float* __restrict__ bq,
                                                   const float* __restrict__ bk,
                                                   const float* __restrict__ bv,
                                                   __bf16* __restrict__ qT,
                                                   __bf16* __restrict__ kT,
                                                   __bf16* __restrict__ vv) {
  __shared__ char smem[SMEM_BYTES];
  __bf16* lds = (__bf16*)smem;
  float* lsr = (float*)smem;
  const int b = blockIdx.z;
  const int id = blockIdx.x;
  const int sel = id >> 7;
  const int r = id & 127;
  const long long sBNC = (long long)NS * CC;
  const long long sBCN = (long long)CC * NS;

  int m0, n0, N;
  const __bf16 *Ap, *Bp;
  __bf16* Cp;
  const float* bias;
  if (sel < 2) {  // q/k: out[n, o] = sum_c hnT[n,c] W[o,c] + b[o]
    m0 = (r >> 2) * TILE;
    n0 = (r & 3) * TILE;
    Ap = hnT + (size_t)b * sBNC + (size_t)m0 * CC;
    Bp = (sel == 0 ? Wq : Wk) + (size_t)n0 * CC;
    Cp = (sel == 0 ? qT : kT) + (size_t)b * sBNC;
    bias = (sel == 0 ? bq : bk);
    N = CC;
  } else {  // v: out[o, n] = sum_c Wv[o,c] hnT[n,c] + bv[o]
    m0 = (r & 3) * TILE;
    n0 = (r >> 2) * TILE;
    Ap = Wv + (size_t)m0 * CC;
    Bp = hnT + (size_t)b * sBNC + (size_t)n0 * CC;
    Cp = vv + (size_t)b * sBCN;
    bias = bv;
    N = NS;
  }

  f32_4 acc[4][2];
#pragma unroll
  for (int i = 0; i < 4; i++)
#pragma unroll
    for (int j = 0; j < 2; j++) acc[i][j] = {0.f, 0.f, 0.f, 0.f};

  gemm_core8(Ap, Bp, CC, CC, CC, lds, acc);

  const int t = threadIdx.x;
  const int lane = t & 63;
  const int lrow = lane & 15, quad = lane >> 4;
  const int wave = t >> 6;
  const int wrow = (wave >> 2) * 64, wcol = (wave & 3) * 32;
#pragma unroll
  for (int i = 0; i < 4; i++)
#pragma unroll
    for (int r2 = 0; r2 < 4; r2++) {
      float rowb = (sel == 2) ? bias[m0 + wrow + i * 16 + quad * 4 + r2] : 0.f;
#pragma unroll
      for (int j = 0; j < 2; j++) {
        float cb = (sel < 2) ? bias[n0 + wcol + j * 16 + lrow] : rowb;
        acc[i][j][r2] += cb;
      }
    }

#pragma unroll
  for (int p = 0; p < 2; p++) {
    __syncthreads();
    stage_acc8(lsr, acc, p);
    __syncthreads();
    drain_bf16_8(lsr, Cp + (size_t)(m0 + p * 64) * N + n0, N);
  }
}

// ---------------- Output projection, FULL K=512, FUSED residual epilogue --------------
// out[b][o][n] = sum_c Wo[o,c] aoT[n,c] + bo[o] + x[b][o][n]  (fp32, direct).
__global__ __launch_bounds__(512, 4) void wo_fused(const __bf16* __restrict__ Wo,
                                                   const __bf16* __restrict__ aoT,
                                                   const float* __restrict__ bo,
                                                   const float* __restrict__ x,
                                                   float* __restrict__ out) {
  __shared__ char smem[SMEM_BYTES];
  __bf16* lds = (__bf16*)smem;
  float* lsr = (float*)smem;
  const int b = blockIdx.z;
  const int m0 = blockIdx.y * TILE;   // over CC (o)
  const int n0 = blockIdx.x * TILE;   // over NS (n)
  const long long sBNC = (long long)NS * CC;
  const long long sBCN = (long long)CC * NS;
  const __bf16* Ap = Wo + (size_t)m0 * CC;
  const __bf16* Bp = aoT + (size_t)b * sBNC + (size_t)n0 * CC;
  const float* xb = x + (size_t)b * sBCN;
  float* ob = out + (size_t)b * sBCN;

  f32_4 acc[4][2];
#pragma unroll
  for (int i = 0; i < 4; i++)
#pragma unroll
    for (int j = 0; j < 2; j++) acc[i][j] = {0.f, 0.f, 0.f, 0.f};

  gemm_core8(Ap, Bp, CC, CC, CC, lds, acc);

  const int t = threadIdx.x;
#pragma unroll
  for (int p = 0; p < 2; p++) {
    __syncthreads();
    stage_acc8(lsr, acc, p);
    __syncthreads();
#pragma unroll
    for (int k2 = 0; k2 < 4; k2++) {
      int idx = k2 * 512 + t;
      int row = idx >> 5, col = (idx & 31) * 4;
      int o = m0 + p * 64 + row;
      f32_4 v = *(const f32_4*)&lsr[row * RSTRIDE + col];
      float bias = bo[o];
      float4 xr = *(const float4*)&xb[(size_t)o * NS + n0 + col];
      float4 rr;
      rr.x = v[0] + bias + xr.x;
      rr.y = v[1] + bias + xr.y;
      rr.z = v[2] + bias + xr.z;
      rr.w = v[3] + bias + xr.w;
      *(float4*)&ob[(size_t)o * NS + n0 + col] = rr;
    }
  }
}

extern "C" void kernel_launch(void* const* d_in, const int* in_sizes, int n_in,
                              void* d_out, int out_size, void* d_ws, size_t ws_size,
                              hipStream_t stream) {
  const float* x = (const float*)d_in[0];
  const float* gamma = (const float*)d_in[1];
  const float* beta = (const float*)d_in[2];
  const float* Wq = (const float*)d_in[3];
  const float* bq = (const float*)d_in[4];
  const float* Wk = (const float*)d_in[5];
  const float* bk = (const float*)d_in[6];
  const float* Wv = (const float*)d_in[7];
  const float* bv = (const float*)d_in[8];
  const float* Wo = (const float*)d_in[9];
  const float* bo = (const float*)d_in[10];
  float* out = (float*)d_out;

  char* ws = (char*)d_ws;
  __bf16* hnT = (__bf16*)(ws + 0);           // [B][NS][CC] 8 MiB
  __bf16* qT  = (__bf16*)(ws + 8388608);
  __bf16* kT  = (__bf16*)(ws + 16777216);
  __bf16* vv  = (__bf16*)(ws + 25165824);    // [B][CC][NS]
  __bf16* aoT = (__bf16*)(ws + 33554432);    // [B][NS][CC]
  __bf16* Eb  = (__bf16*)(ws + 41943040);    // [B][NS][NS] 64 MiB
  __bf16* Wqb = (__bf16*)(ws + 109051904);   // dead after qkv -> reused as lsum
  __bf16* Wkb = (__bf16*)(ws + 109576192);
  __bf16* Wvb = (__bf16*)(ws + 110100480);
  __bf16* Wob = (__bf16*)(ws + 110624768);
  float* stats = (float*)(ws + 111149056);   // per-chunk (S,Q) partials, 512 floats
  float* lsum = (float*)(ws + 109051904);    // [B][NS] fp32, aliases dead Wqb

  const float scale = 0.044194173824159216f;  // 512^-0.5

  // Opt-in to 128 KiB dynamic LDS for e_gemm (one-time, host-side, graph-safe).
  static int smem_attr_set = 0;
  if (!smem_attr_set) {
    hipFuncSetAttribute(reinterpret_cast<const void*>(e_gemm256),
                        hipFuncAttributeMaxDynamicSharedMemorySize, SMEM256);
    smem_attr_set = 1;
  }

  // Merged weight-cvt + GN stats partials (one dispatch, disjoint outputs).
  prep<<<1024 + 4 * BB * NGROUP, 256, 0, stream>>>(Wq, Wk, Wv, Wo, Wqb, Wkb, Wvb, Wob, x, stats);
  gn_apply_t<<<dim3(NS / 32, CC / 32, BB), dim3(32, 8), 0, stream>>>(x, stats, gamma, beta, hnT);

  // Fused Q/K/V projections: 768 blocks (core A, double-buffered).
  qkv_gemm<<<dim3(384, 1, BB), 512, 0, stream>>>(hnT, Wqb, Wkb, Wvb, bq, bk, bv, qT, kT, vv);

  // Zero row-sum accumulator (Wqb is dead now), then E-GEMM (core F).
  hipMemsetAsync(lsum, 0, BB * NS * sizeof(float), stream);
  e_gemm256<<<512, 512, SMEM256, stream>>>(qT, kT, Eb, lsum, scale);

  // attn*V full-K with fused softmax division (256 blocks, core A; no reduce pass).
  ao_full<<<256, 512, 0, stream>>>(Eb, vv, lsum, aoT);

  // Output projection FULL-K with fused bias + residual (fp32 out, one dispatch).
  wo_fused<<<dim3(NS / TILE, CC / TILE, BB), 512, 0, stream>>>(Wob, aoT, bo, x, out);
}

// Round 14
// 219.113 us; speedup vs baseline: 1.0490x; 1.0490x over previous
//
#include <hip/hip_runtime.h>

// Problem constants: x [B=2, C=512, H=64, W=64], 32 groups, N = H*W = 4096.
#define BB 2
#define CC 512
#define NS 4096
#define NGROUP 32
#define TILE 128
#define RSTRIDE 132   // repack LDS row stride (floats): 128 + 4 pad

typedef __bf16 bf16_8 __attribute__((ext_vector_type(8)));
typedef __bf16 bf16_4 __attribute__((ext_vector_type(4)));
typedef float f32_4 __attribute__((ext_vector_type(4)));

#define SMEM_BYTES 65536   // core-A kernels: 2 x (16KB A + 16KB B) double-buffer
#define SMEM256 131072     // core C/F kernels: 2 x (32KB A + 32KB B) double-buffer

__device__ __forceinline__ void gld_lds16(const __bf16* g, __bf16* l) {
  __builtin_amdgcn_global_load_lds(
      (const __attribute__((address_space(1))) unsigned int*)g,
      (__attribute__((address_space(3))) unsigned int*)l, 16, 0, 0);
}

// ---------------- prep: weight cvt (0-1023) + GN stats partials (1024-1279) ----------
// ---------------- + lsum zeroing (1280-1287) ------------------------------------------
// Stats: per-(group, quarter-chunk) PARTIAL sums stored plain to
// st[g*8 + ch*2 + {0,1}]; gn_apply_t sums the 4 partials. lsum (own slot, no
// longer aliasing Wqb) is zeroed here, removing the hipMemsetAsync dispatch.
__global__ __launch_bounds__(256) void prep(const float* __restrict__ w0, const float* __restrict__ w1,
                                            const float* __restrict__ w2, const float* __restrict__ w3,
                                            __bf16* __restrict__ o0, __bf16* __restrict__ o1,
                                            __bf16* __restrict__ o2, __bf16* __restrict__ o3,
                                            const float* __restrict__ x,
                                            float* __restrict__ st,
                                            float* __restrict__ lz) {
  const int bid = blockIdx.x;
  if (bid >= 1280) {   // zero lsum: 8 blocks x 256 threads x 1 float4 = 32 KB
    ((float4*)lz)[(bid - 1280) * 256 + threadIdx.x] = make_float4(0.f, 0.f, 0.f, 0.f);
    return;
  }
  if (bid >= 1024) {
    const int idx = bid - 1024;
    const int g = idx >> 2;               // 0..63: b*32+group
    const int ch = idx & 3;               // quarter-chunk of the group
    const float4* p = (const float4*)(x + (size_t)g * 65536 + (size_t)ch * 16384);
    float s = 0.f, q = 0.f;
    for (int i = threadIdx.x; i < 4096; i += 256) {
      float4 v = p[i];
      s += v.x + v.y + v.z + v.w;
      q += v.x * v.x + v.y * v.y + v.z * v.z + v.w * v.w;
    }
#pragma unroll
    for (int off = 32; off > 0; off >>= 1) {
      s += __shfl_down(s, off, 64);
      q += __shfl_down(q, off, 64);
    }
    __shared__ float ls[4], lq[4];
    int wave = threadIdx.x >> 6, lane = threadIdx.x & 63;
    if (lane == 0) { ls[wave] = s; lq[wave] = q; }
    __syncthreads();
    if (threadIdx.x == 0) {
      st[g * 8 + ch * 2 + 0] = ls[0] + ls[1] + ls[2] + ls[3];
      st[g * 8 + ch * 2 + 1] = lq[0] + lq[1] + lq[2] + lq[3];
    }
    return;
  }
  int tsel = bid >> 8;
  int i = (bid & 255) * 256 + threadIdx.x;
  const float* src = tsel == 0 ? w0 : tsel == 1 ? w1 : tsel == 2 ? w2 : w3;
  __bf16* dst = tsel == 0 ? o0 : tsel == 1 ? o1 : tsel == 2 ? o2 : o3;
  float4 v = ((const float4*)src)[i];
  bf16_4 r;
  r[0] = (__bf16)v.x; r[1] = (__bf16)v.y; r[2] = (__bf16)v.z; r[3] = (__bf16)v.w;
  ((bf16_4*)dst)[i] = r;
}

// Normalize + transpose: x[b][c][n] (fp32) -> hnT[b][n][c] (bf16), 32x32 tiles via LDS.
// Finalizes mean/rstd from the 4 per-chunk (S,Q) partials.
__global__ __launch_bounds__(256) void gn_apply_t(const float* __restrict__ x,
                                                  const float* __restrict__ st,
                                                  const float* __restrict__ gamma,
                                                  const float* __restrict__ beta,
                                                  __bf16* __restrict__ hnT) {
  __shared__ float tile[32][33];
  int b = blockIdx.z;
  int c0 = blockIdx.y * 32;
  int n0 = blockIdx.x * 32;
  int tx = threadIdx.x;  // 0..31
  int ty = threadIdx.y;  // 0..7
  const float* xb = x + (size_t)b * CC * NS;
#pragma unroll
  for (int i = 0; i < 4; i++) {
    int c = c0 + ty + i * 8;
    int g8 = (b * NGROUP + (c >> 4)) * 8;
    float S = st[g8 + 0] + st[g8 + 2] + st[g8 + 4] + st[g8 + 6];
    float Q = st[g8 + 1] + st[g8 + 3] + st[g8 + 5] + st[g8 + 7];
    float mean = S * (1.f / 65536.f);
    float var = Q * (1.f / 65536.f) - mean * mean;
    float rstd = rsqrtf(var + 1e-6f);
    float v = xb[(size_t)c * NS + n0 + tx];
    tile[ty + i * 8][tx] = (v - mean) * rstd * gamma[c] + beta[c];
  }
  __syncthreads();
  __bf16* out = hnT + (size_t)b * NS * CC;
#pragma unroll
  for (int i = 0; i < 4; i++) {
    int n = n0 + ty + i * 8;
    out[(size_t)n * CC + c0 + tx] = (__bf16)tile[tx][ty + i * 8];
  }
}

// ======== Core A (double-buffered): 512 threads, 8 waves, 64x32/wave, BK=64 ========
__device__ __forceinline__ void gemm_core8(const __bf16* __restrict__ A, const __bf16* __restrict__ B,
                                           int K, int lda, int ldb,
                                           __bf16* lds, f32_4 (&acc)[4][2]) {
  const int t = threadIdx.x;
  const int lane = t & 63;
  const int wave = t >> 6;
  const int lrow = lane & 15, quad = lane >> 4;
  const int wrow = (wave >> 2) * 64, wcol = (wave & 3) * 32;
  const int co = (quad ^ ((lrow >> 1) & 3)) * 8;   // swizzled read chunk
  const int r0 = t >> 2;                            // 0..127: staged row
  const int kp = ((t & 3) ^ ((t >> 3) & 3)) * 8;   // swizzled staged global chunk
  const __bf16* pA = A + (size_t)r0 * lda + kp;
  const __bf16* pB = B + (size_t)r0 * ldb + kp;
  // prologue: stage k0=0 into buf0
  {
    __bf16* lA = lds;
    __bf16* lB = lds + 8192;
    gld_lds16(pA,      &lA[t * 8]);
    gld_lds16(pA + 32, &lA[4096 + t * 8]);
    gld_lds16(pB,      &lB[t * 8]);
    gld_lds16(pB + 32, &lB[4096 + t * 8]);
  }
  int buf = 0;
  for (int k0 = 0; k0 < K; k0 += 64, buf ^= 1) {
    __syncthreads();   // drains buf's loads (prefetched last iter); protects buf^1 overwrite
    if (k0 + 64 < K) {
      __bf16* lA = lds + (buf ^ 1) * 16384;
      __bf16* lB = lA + 8192;
      gld_lds16(pA + k0 + 64, &lA[t * 8]);
      gld_lds16(pA + k0 + 96, &lA[4096 + t * 8]);
      gld_lds16(pB + k0 + 64, &lB[t * 8]);
      gld_lds16(pB + k0 + 96, &lB[4096 + t * 8]);
    }
    const __bf16* bA = lds + buf * 16384;
    const __bf16* bB = bA + 8192;
#pragma unroll
    for (int ks = 0; ks < 2; ks++) {
      const __bf16* la = bA + ks * 4096;
      const __bf16* lb = bB + ks * 4096;
      bf16_8 af[4], bfr[2];
#pragma unroll
      for (int i = 0; i < 4; i++)
        af[i] = *(const bf16_8*)&la[(wrow + i * 16 + lrow) * 32 + co];
#pragma unroll
      for (int j = 0; j < 2; j++)
        bfr[j] = *(const bf16_8*)&lb[(wcol + j * 16 + lrow) * 32 + co];
#pragma unroll
      for (int i = 0; i < 4; i++)
#pragma unroll
        for (int j = 0; j < 2; j++)
          acc[i][j] = __builtin_amdgcn_mfma_f32_16x16x32_bf16(af[i], bfr[j], acc[i][j], 0, 0, 0);
    }
  }
}

// Repack epilogue for core A (512 threads). lsr unions with dead staging LDS.
__device__ __forceinline__ void stage_acc8(float* ls, const f32_4 (&acc)[4][2], int pass) {
  const int t = threadIdx.x;
  const int lane = t & 63, wave = t >> 6;
  const int lrow = lane & 15, quad = lane >> 4;
  const int wrow = (wave >> 2) * 64, wcol = (wave & 3) * 32;
  if ((wrow >> 6) == pass) {
#pragma unroll
    for (int i = 0; i < 4; i++)
#pragma unroll
      for (int r = 0; r < 4; r++)
#pragma unroll
        for (int jj = 0; jj < 2; jj++)
          ls[(i * 16 + quad * 4 + r) * RSTRIDE + wcol + jj * 16 + lrow] = acc[i][jj][r];
  }
}

__device__ __forceinline__ void drain_bf16_8(const float* ls, __bf16* gdst, int ldg) {
  const int t = threadIdx.x;
#pragma unroll
  for (int k2 = 0; k2 < 4; k2++) {
    int idx = k2 * 512 + t;
    int row = idx >> 5, col = (idx & 31) * 4;
    f32_4 v = *(const f32_4*)&ls[row * RSTRIDE + col];
    bf16_4 o;
    o[0] = (__bf16)v[0]; o[1] = (__bf16)v[1]; o[2] = (__bf16)v[2]; o[3] = (__bf16)v[3];
    *(bf16_4*)&gdst[(size_t)row * ldg + col] = o;
  }
}

// ======== Core C v1 (quadrant phases): 256x256 tile, 512 threads, BK=64 ========
// Kept for ao256 (proven config; full-K ao variant measured WORSE — E re-read
// traffic quadruples, round-13 ledger).
__device__ __forceinline__ void gemm_core256(const __bf16* __restrict__ A,
                                             const __bf16* __restrict__ B,
                                             int K, int lda, int ldb,
                                             __bf16* lds, f32_4 (&acc)[8][4]) {
  const int t = threadIdx.x;
  const int lane = t & 63;
  const int wave = t >> 6;
  const int lrow = lane & 15, quad = lane >> 4;
  const int wm = wave >> 2, wn = wave & 3;
  const int r0 = t >> 2;                            // 0..127: staged row within half
  const int kp = ((t & 3) ^ ((t >> 3) & 3)) * 8;    // swizzled staged global chunk
  const __bf16* gA0 = A + (size_t)r0 * lda + kp;
  const __bf16* gA1 = A + (size_t)(r0 + 128) * lda + kp;
  const __bf16* gB0 = B + (size_t)r0 * ldb + kp;
  const __bf16* gB1 = B + (size_t)(r0 + 128) * ldb + kp;
  const int co = (quad ^ ((lrow >> 1) & 3)) * 8;    // swizzled read chunk
  const int aoff = (wm * 128 + lrow) * 32 + co;
  const int boff = 16384 + (wn * 64 + lrow) * 32 + co;
  const int KT = K >> 6;   // number of 64-wide K-tiles (must be even)

#define STG(bufv, isB, srcp, hh, ktv)                                         \
  {                                                                           \
    __bf16* d_ = lds + (bufv) * 32768 + (isB) * 16384 + (hh) * 4096 + t * 8;  \
    const __bf16* s_ = (srcp) + (ktv) * 64;                                   \
    gld_lds16(s_, d_);                                                        \
    gld_lds16(s_ + 32, d_ + 8192);                                            \
  }
#define LOAD_AF(IH)                                                           \
  _Pragma("unroll") for (int i = 0; i < 4; i++)                               \
      _Pragma("unroll") for (int ks = 0; ks < 2; ks++)                        \
          af[i][ks] = *(const bf16_8*)&bb[aoff + ((IH) * 4 + i) * 512 + ks * 8192];
#define LOAD_BV(J0)                                                           \
  _Pragma("unroll") for (int j = 0; j < 2; j++)                               \
      _Pragma("unroll") for (int ks = 0; ks < 2; ks++)                        \
          bv[(J0) + j][ks] = *(const bf16_8*)&bb[boff + ((J0) + j) * 512 + ks * 8192];
#define MFMA16(I0, J0)                                                        \
  _Pragma("unroll") for (int ks = 0; ks < 2; ks++)                            \
      _Pragma("unroll") for (int i = 0; i < 4; i++)                           \
          _Pragma("unroll") for (int j = 0; j < 2; j++)                       \
              acc[(I0) + i][(J0) + j] = __builtin_amdgcn_mfma_f32_16x16x32_bf16( \
                  af[i][ks], bv[(J0) + j][ks], acc[(I0) + i][(J0) + j], 0, 0, 0);
#define PHASE_BEGIN()                                                         \
  __builtin_amdgcn_s_barrier();                                               \
  asm volatile("s_waitcnt lgkmcnt(0)" ::: "memory");                          \
  __builtin_amdgcn_sched_barrier(0);                                          \
  __builtin_amdgcn_s_setprio(1);
#define PHASE_END()                                                           \
  __builtin_amdgcn_s_setprio(0);                                              \
  __builtin_amdgcn_s_barrier();

  STG(0, 0, gA0, 0, 0)
  STG(0, 0, gA1, 1, 0)
  STG(0, 1, gB0, 0, 0)
  STG(0, 1, gB1, 1, 0)
  STG(1, 1, gB0, 0, 1)
  STG(1, 1, gB1, 1, 1)
  asm volatile("s_waitcnt vmcnt(4)" ::: "memory");   // buf0's 8 loads done
  __builtin_amdgcn_s_barrier();

  for (int it = 0; it < (KT >> 1); ++it) {
#pragma unroll
    for (int h = 0; h < 2; ++h) {
      const int kt = 2 * it + h;
      const __bf16* bb = lds + h * 32768;
      bf16_8 af[4][2], bv[4][2];
      // ---- Pa ----
      LOAD_AF(0)
      LOAD_BV(0)
      if (kt + 1 < KT) STG(h ^ 1, 0, gA0, 0, kt + 1)
      PHASE_BEGIN()
      MFMA16(0, 0)
      PHASE_END()
      // ---- Pb ----
      LOAD_BV(2)
      if (kt + 1 < KT) STG(h ^ 1, 0, gA1, 1, kt + 1)
      PHASE_BEGIN()
      MFMA16(0, 2)
      PHASE_END()
      // ---- Pc ----
      LOAD_AF(1)
      if (kt + 2 < KT) STG(h, 1, gB0, 0, kt + 2)
      PHASE_BEGIN()
      MFMA16(4, 0)
      PHASE_END()
      // ---- Pd ----
      if (kt + 2 < KT) STG(h, 1, gB1, 1, kt + 2)
      PHASE_BEGIN()
      MFMA16(4, 2)
      __builtin_amdgcn_s_setprio(0);
      if (kt + 2 < KT) {
        asm volatile("s_waitcnt vmcnt(4)" ::: "memory");   // counted: kt+1 data landed
      } else {
        asm volatile("s_waitcnt vmcnt(0)" ::: "memory");   // tail drain (once)
      }
      __builtin_amdgcn_s_barrier();
    }
  }
#undef STG
#undef LOAD_AF
#undef LOAD_BV
#undef MFMA16
#undef PHASE_BEGIN
#undef PHASE_END
}

// ======== Core F: 256x256 tile, 512 threads, BK=64, ONE sync per K-tile ========
__device__ __forceinline__ void gemm_coreF(const __bf16* __restrict__ A,
                                           const __bf16* __restrict__ B,
                                           int K, int lda, int ldb,
                                           __bf16* lds, f32_4 (&acc)[8][4]) {
  const int t = threadIdx.x;
  const int lane = t & 63;
  const int wave = t >> 6;
  const int lrow = lane & 15, quad = lane >> 4;
  const int wm = wave >> 2, wn = wave & 3;
  const int r0 = t >> 2;                            // 0..127: staged row within half
  const int kp = ((t & 3) ^ ((t >> 3) & 3)) * 8;    // swizzled staged global chunk
  const __bf16* gA0 = A + (size_t)r0 * lda + kp;
  const __bf16* gA1 = A + (size_t)(r0 + 128) * lda + kp;
  const __bf16* gB0 = B + (size_t)r0 * ldb + kp;
  const __bf16* gB1 = B + (size_t)(r0 + 128) * ldb + kp;
  const int co = (quad ^ ((lrow >> 1) & 3)) * 8;    // swizzled read chunk
  const int aoff = (wm * 128 + lrow) * 32 + co;
  const int boff = 16384 + (wn * 64 + lrow) * 32 + co;
  const int KT = K >> 6;

  // prologue: stage K-tile 0 into buf0 (8 gld_lds)
  {
    __bf16* d = lds + t * 8;
    gld_lds16(gA0,      d);            // A ks0 rows 0-127
    gld_lds16(gA1,      d + 4096);     // A ks0 rows 128-255
    gld_lds16(gA0 + 32, d + 8192);     // A ks1 rows 0-127
    gld_lds16(gA1 + 32, d + 12288);    // A ks1 rows 128-255
    gld_lds16(gB0,      d + 16384);    // B ks0 rows 0-127
    gld_lds16(gB1,      d + 20480);    // B ks0 rows 128-255
    gld_lds16(gB0 + 32, d + 24576);    // B ks1 rows 0-127
    gld_lds16(gB1 + 32, d + 28672);    // B ks1 rows 128-255
  }
  int buf = 0;
  for (int kt = 0; kt < KT; ++kt, buf ^= 1) {
    __syncthreads();   // drains prev stage (landed during prev tile); WAR-safe
    if (kt + 1 < KT) {
      __bf16* d = lds + (buf ^ 1) * 32768 + t * 8;
      const int go = (kt + 1) * 64;
      gld_lds16(gA0 + go,      d);
      gld_lds16(gA1 + go,      d + 4096);
      gld_lds16(gA0 + go + 32, d + 8192);
      gld_lds16(gA1 + go + 32, d + 12288);
      gld_lds16(gB0 + go,      d + 16384);
      gld_lds16(gB1 + go,      d + 20480);
      gld_lds16(gB0 + go + 32, d + 24576);
      gld_lds16(gB1 + go + 32, d + 28672);
    }
    const __bf16* bb = lds + buf * 32768;
#pragma unroll
    for (int ks = 0; ks < 2; ks++) {
      bf16_8 af[8], bv[4];
#pragma unroll
      for (int f = 0; f < 8; f++)
        af[f] = *(const bf16_8*)&bb[aoff + f * 512 + ks * 8192];
#pragma unroll
      for (int j = 0; j < 4; j++)
        bv[j] = *(const bf16_8*)&bb[boff + j * 512 + ks * 8192];
#pragma unroll
      for (int f = 0; f < 8; f++)
#pragma unroll
        for (int j = 0; j < 4; j++)
          acc[f][j] = __builtin_amdgcn_mfma_f32_16x16x32_bf16(af[f], bv[j], acc[f][j], 0, 0, 0);
    }
  }
}

// ---------------- S-GEMM with fused exp + row-sum (core F, 512 blocks) ---------------
__global__ __launch_bounds__(512, 2) void e_gemm256(const __bf16* __restrict__ qT,
                                                    const __bf16* __restrict__ kT,
                                                    __bf16* __restrict__ E,
                                                    float* __restrict__ l,
                                                    float scale) {
  extern __shared__ __bf16 ldsdyn[];
  const int bid = blockIdx.x;
  const int lin = (bid & 7) * 64 + (bid >> 3);   // XCD-chunked (512 % 8 == 0)
  const int b = lin >> 8;
  const int rm = lin & 255;
  // 8x4 tile rectangles so the 32 concurrent blocks of an XCD share panels.
  const int R = rm >> 5, s = rm & 31;
  const int mt = (R >> 2) * 8 + (s >> 2);
  const int nt = (R & 3) * 4 + (s & 3);
  const int m0 = mt * 256, n0 = nt * 256;
  const long long sBNC = (long long)NS * CC;
  const long long sBNN = (long long)NS * NS;
  const __bf16* Ap = qT + (size_t)b * sBNC + (size_t)m0 * CC;
  const __bf16* Bp = kT + (size_t)b * sBNC + (size_t)n0 * CC;

  f32_4 acc[8][4];
#pragma unroll
  for (int i = 0; i < 8; i++)
#pragma unroll
    for (int j = 0; j < 4; j++) acc[i][j] = {0.f, 0.f, 0.f, 0.f};

  gemm_coreF(Ap, Bp, CC, CC, CC, ldsdyn, acc);

  const int t = threadIdx.x;
  const int lane = t & 63, wave = t >> 6;
  const int lrow = lane & 15, quad = lane >> 4;
  const int wm = wave >> 2, wn = wave & 3;
  __bf16* Ep = E + (size_t)b * sBNN;
  float* lp = l + (size_t)b * NS;
#pragma unroll
  for (int i = 0; i < 8; i++) {
#pragma unroll
    for (int r = 0; r < 4; r++) {
      int gm = m0 + wm * 128 + i * 16 + quad * 4 + r;
      float rp = 0.f;
#pragma unroll
      for (int j = 0; j < 4; j++) {
        int gn = n0 + wn * 64 + j * 16 + lrow;
        float ev = __expf(acc[i][j][r] * scale);
        rp += ev;
        Ep[(size_t)gm * NS + gn] = (__bf16)ev;
      }
      rp += __shfl_down(rp, 8, 16);
      rp += __shfl_down(rp, 4, 16);
      rp += __shfl_down(rp, 2, 16);
      rp += __shfl_down(rp, 1, 16);
      if (lrow == 0) atomicAdd(&lp[gm], rp);
    }
  }
}

// ---------------- attn*V split-K=4 GEMM (core C v1, 256 blocks = 1 round) ----------
__global__ __launch_bounds__(512, 2) void ao256(const __bf16* __restrict__ E,
                                                const __bf16* __restrict__ vv,
                                                __bf16* __restrict__ p0,
                                                __bf16* __restrict__ p1,
                                                __bf16* __restrict__ p2,
                                                __bf16* __restrict__ p3) {
  extern __shared__ __bf16 ldsdyn[];
  const int bid = blockIdx.x;
  const int lin = (bid & 7) * 32 + (bid >> 3);   // XCD-chunked (256 % 8 == 0)
  const int split = lin >> 6;                    // 0..3: K-quarter
  const int rem = lin & 63;
  const int b = rem >> 5;
  const int mt = (rem & 31) >> 1;                // 0..15 over NS rows
  const int nt = rem & 1;                        // 0..1 over CC cols
  const int m0 = mt * 256, n0 = nt * 256;
  const long long sBNN = (long long)NS * NS;
  const long long sBCN = (long long)CC * NS;
  const long long sBNC = (long long)NS * CC;
  const __bf16* Ap = E + (size_t)b * sBNN + (size_t)m0 * NS + (size_t)split * 1024;
  const __bf16* Bp = vv + (size_t)b * sBCN + (size_t)n0 * NS + (size_t)split * 1024;
  __bf16* Cp = (split == 0 ? p0 : split == 1 ? p1 : split == 2 ? p2 : p3) + (size_t)b * sBNC;

  f32_4 acc[8][4];
#pragma unroll
  for (int i = 0; i < 8; i++)
#pragma unroll
    for (int j = 0; j < 4; j++) acc[i][j] = {0.f, 0.f, 0.f, 0.f};

  gemm_core256(Ap, Bp, 1024, NS, NS, ldsdyn, acc);

  const int t = threadIdx.x;
  const int lane = t & 63, wave = t >> 6;
  const int lrow = lane & 15, quad = lane >> 4;
  const int wm = wave >> 2, wn = wave & 3;
#pragma unroll
  for (int i = 0; i < 8; i++) {
#pragma unroll
    for (int r = 0; r < 4; r++) {
      int gm = m0 + wm * 128 + i * 16 + quad * 4 + r;
#pragma unroll
      for (int j = 0; j < 4; j++) {
        int gn = n0 + wn * 64 + j * 16 + lrow;
        Cp[(size_t)gm * CC + gn] = (__bf16)acc[i][j][r];
      }
    }
  }
}

// ---------------- Fused Q/K/V projections (one dispatch, 768 blocks, core A) ----------
__global__ __launch_bounds__(512, 4) void qkv_gemm(const __bf16* __restrict__ hnT,
                                                   const __bf16* __restrict__ Wq,
                                                   const __bf16* __restrict__ Wk,
                                                   const __bf16* __restrict__ Wv,
                                                   const float* __restrict__ bq,
                                                   const float* __restrict__ bk,
                                                   const float* __restrict__ bv,
                                                   __bf16* __restrict__ qT,
                                                   __bf16* __restrict__ kT,
                                                   __bf16* __restrict__ vv) {
  __shared__ char smem[SMEM_BYTES];
  __bf16* lds = (__bf16*)smem;
  float* lsr = (float*)smem;
  const int b = blockIdx.z;
  const int id = blockIdx.x;
  const int sel = id >> 7;
  const int r = id & 127;
  const long long sBNC = (long long)NS * CC;
  const long long sBCN = (long long)CC * NS;

  int m0, n0, N;
  const __bf16 *Ap, *Bp;
  __bf16* Cp;
  const float* bias;
  if (sel < 2) {  // q/k: out[n, o] = sum_c hnT[n,c] W[o,c] + b[o]
    m0 = (r >> 2) * TILE;
    n0 = (r & 3) * TILE;
    Ap = hnT + (size_t)b * sBNC + (size_t)m0 * CC;
    Bp = (sel == 0 ? Wq : Wk) + (size_t)n0 * CC;
    Cp = (sel == 0 ? qT : kT) + (size_t)b * sBNC;
    bias = (sel == 0 ? bq : bk);
    N = CC;
  } else {  // v: out[o, n] = sum_c Wv[o,c] hnT[n,c] + bv[o]
    m0 = (r & 3) * TILE;
    n0 = (r >> 2) * TILE;
    Ap = Wv + (size_t)m0 * CC;
    Bp = hnT + (size_t)b * sBNC + (size_t)n0 * CC;
    Cp = vv + (size_t)b * sBCN;
    bias = bv;
    N = NS;
  }

  f32_4 acc[4][2];
#pragma unroll
  for (int i = 0; i < 4; i++)
#pragma unroll
    for (int j = 0; j < 2; j++) acc[i][j] = {0.f, 0.f, 0.f, 0.f};

  gemm_core8(Ap, Bp, CC, CC, CC, lds, acc);

  const int t = threadIdx.x;
  const int lane = t & 63;
  const int lrow = lane & 15, quad = lane >> 4;
  const int wave = t >> 6;
  const int wrow = (wave >> 2) * 64, wcol = (wave & 3) * 32;
#pragma unroll
  for (int i = 0; i < 4; i++)
#pragma unroll
    for (int r2 = 0; r2 < 4; r2++) {
      float rowb = (sel == 2) ? bias[m0 + wrow + i * 16 + quad * 4 + r2] : 0.f;
#pragma unroll
      for (int j = 0; j < 2; j++) {
        float cb = (sel < 2) ? bias[n0 + wcol + j * 16 + lrow] : rowb;
        acc[i][j][r2] += cb;
      }
    }

#pragma unroll
  for (int p = 0; p < 2; p++) {
    __syncthreads();
    stage_acc8(lsr, acc, p);
    __syncthreads();
    drain_bf16_8(lsr, Cp + (size_t)(m0 + p * 64) * N + n0, N);
  }
}

// (p0+p1+p2+p3)/l[row] -> aoT (bf16). p3 may alias the output (elementwise RAW).
__global__ __launch_bounds__(256) void reduce_ao4(const __bf16* __restrict__ p0,
                                                  const __bf16* __restrict__ p1,
                                                  const __bf16* __restrict__ p2,
                                                  const __bf16* __restrict__ p3,
                                                  const float* __restrict__ l,
                                                  __bf16* __restrict__ o) {
  int i = blockIdx.x * 256 + threadIdx.x;   // bf16_8 units, [B][NS][CC]
  int row = i >> 6;                          // 64 vecs per row of 512 chans
  float inv = 1.f / l[row];
  bf16_8 a = ((const bf16_8*)p0)[i];
  bf16_8 c = ((const bf16_8*)p1)[i];
  bf16_8 d = ((const bf16_8*)p2)[i];
  bf16_8 e = ((const bf16_8*)p3)[i];
  bf16_8 r;
#pragma unroll
  for (int k = 0; k < 8; k++)
    r[k] = (__bf16)(((float)a[k] + (float)c[k] + (float)d[k] + (float)e[k]) * inv);
  ((bf16_8*)o)[i] = r;
}

// ---------------- Output projection, FULL K=512, FUSED residual epilogue --------------
// out[b][o][n] = sum_c Wo[o,c] aoT[n,c] + bo[o] + x[b][o][n]  (fp32, direct).
__global__ __launch_bounds__(512, 4) void wo_fused(const __bf16* __restrict__ Wo,
                                                   const __bf16* __restrict__ aoT,
                                                   const float* __restrict__ bo,
                                                   const float* __restrict__ x,
                                                   float* __restrict__ out) {
  __shared__ char smem[SMEM_BYTES];
  __bf16* lds = (__bf16*)smem;
  float* lsr = (float*)smem;
  const int b = blockIdx.z;
  const int m0 = blockIdx.y * TILE;   // over CC (o)
  const int n0 = blockIdx.x * TILE;   // over NS (n)
  const long long sBNC = (long long)NS * CC;
  const long long sBCN = (long long)CC * NS;
  const __bf16* Ap = Wo + (size_t)m0 * CC;
  const __bf16* Bp = aoT + (size_t)b * sBNC + (size_t)n0 * CC;
  const float* xb = x + (size_t)b * sBCN;
  float* ob = out + (size_t)b * sBCN;

  f32_4 acc[4][2];
#pragma unroll
  for (int i = 0; i < 4; i++)
#pragma unroll
    for (int j = 0; j < 2; j++) acc[i][j] = {0.f, 0.f, 0.f, 0.f};

  gemm_core8(Ap, Bp, CC, CC, CC, lds, acc);

  const int t = threadIdx.x;
#pragma unroll
  for (int p = 0; p < 2; p++) {
    __syncthreads();
    stage_acc8(lsr, acc, p);
    __syncthreads();
#pragma unroll
    for (int k2 = 0; k2 < 4; k2++) {
      int idx = k2 * 512 + t;
      int row = idx >> 5, col = (idx & 31) * 4;
      int o = m0 + p * 64 + row;
      f32_4 v = *(const f32_4*)&lsr[row * RSTRIDE + col];
      float bias = bo[o];
      float4 xr = *(const float4*)&xb[(size_t)o * NS + n0 + col];
      float4 rr;
      rr.x = v[0] + bias + xr.x;
      rr.y = v[1] + bias + xr.y;
      rr.z = v[2] + bias + xr.z;
      rr.w = v[3] + bias + xr.w;
      *(float4*)&ob[(size_t)o * NS + n0 + col] = rr;
    }
  }
}

extern "C" void kernel_launch(void* const* d_in, const int* in_sizes, int n_in,
                              void* d_out, int out_size, void* d_ws, size_t ws_size,
                              hipStream_t stream) {
  const float* x = (const float*)d_in[0];
  const float* gamma = (const float*)d_in[1];
  const float* beta = (const float*)d_in[2];
  const float* Wq = (const float*)d_in[3];
  const float* bq = (const float*)d_in[4];
  const float* Wk = (const float*)d_in[5];
  const float* bk = (const float*)d_in[6];
  const float* Wv = (const float*)d_in[7];
  const float* bv = (const float*)d_in[8];
  const float* Wo = (const float*)d_in[9];
  const float* bo = (const float*)d_in[10];
  float* out = (float*)d_out;

  char* ws = (char*)d_ws;
  __bf16* hnT = (__bf16*)(ws + 0);           // [B][NS][CC] 8 MiB; later ao partial p0
  __bf16* qT  = (__bf16*)(ws + 8388608);     // later p1
  __bf16* kT  = (__bf16*)(ws + 16777216);    // later p2
  __bf16* vv  = (__bf16*)(ws + 25165824);    // [B][CC][NS]
  __bf16* aoT = (__bf16*)(ws + 33554432);    // [B][NS][CC]; doubles as p3 (RAW-safe)
  __bf16* Eb  = (__bf16*)(ws + 41943040);    // [B][NS][NS] 64 MiB
  __bf16* Wqb = (__bf16*)(ws + 109051904);
  __bf16* Wkb = (__bf16*)(ws + 109576192);
  __bf16* Wvb = (__bf16*)(ws + 110100480);
  __bf16* Wob = (__bf16*)(ws + 110624768);
  float* stats = (float*)(ws + 111149056);   // per-chunk (S,Q) partials, 512 floats
  float* lsum = (float*)(ws + 111153152);    // [B][NS] fp32, own slot (prep-zeroed)
  __bf16* p0 = hnT;
  __bf16* p1 = qT;
  __bf16* p2 = kT;
  __bf16* p3 = aoT;

  const float scale = 0.044194173824159216f;  // 512^-0.5

  // Opt-in to 128 KiB dynamic LDS (one-time, host-side, graph-capture safe).
  static int smem_attr_set = 0;
  if (!smem_attr_set) {
    hipFuncSetAttribute(reinterpret_cast<const void*>(e_gemm256),
                        hipFuncAttributeMaxDynamicSharedMemorySize, SMEM256);
    hipFuncSetAttribute(reinterpret_cast<const void*>(ao256),
                        hipFuncAttributeMaxDynamicSharedMemorySize, SMEM256);
    smem_attr_set = 1;
  }

  // Merged weight-cvt + GN stats partials + lsum zeroing (one dispatch).
  prep<<<1024 + 4 * BB * NGROUP + 8, 256, 0, stream>>>(Wq, Wk, Wv, Wo, Wqb, Wkb, Wvb, Wob,
                                                       x, stats, lsum);
  gn_apply_t<<<dim3(NS / 32, CC / 32, BB), dim3(32, 8), 0, stream>>>(x, stats, gamma, beta, hnT);

  // Fused Q/K/V projections: 768 blocks (core A, double-buffered).
  qkv_gemm<<<dim3(384, 1, BB), 512, 0, stream>>>(hnT, Wqb, Wkb, Wvb, bq, bk, bv, qT, kT, vv);

  // E-GEMM (core F; lsum already zeroed by prep).
  e_gemm256<<<512, 512, SMEM256, stream>>>(qT, kT, Eb, lsum, scale);

  // aoT partials = E * v^T over quarter-K splits (256 blocks, core C v1).
  ao256<<<256, 512, SMEM256, stream>>>(Eb, vv, p0, p1, p2, p3);
  reduce_ao4<<<2048, 256, 0, stream>>>(p0, p1, p2, p3, lsum, aoT);

  // Output projection FULL-K with fused bias + residual (fp32 out, one dispatch).
  wo_fused<<<dim3(NS / TILE, CC / TILE, BB), 512, 0, stream>>>(Wob, aoT, bo, x, out);
}